// Round 10
// baseline (277.610 us; speedup 1.0000x reference)
//
#include <hip/hip_runtime.h>
#include <hip/hip_bf16.h>
#include <stdint.h>

#define NNODE  17
#define FDIM   64
#define NBLOCK 1024
#define GPW    16           // graphs per wave: 1024 blk x 4 waves x 16 = 65536
#define SROW   68           // wave-strip col stride in u16 (136 B; conflict-free)
#define WSTR   132          // W2T staging stride in u16

typedef __attribute__((ext_vector_type(4)))  short short4v;
typedef __attribute__((ext_vector_type(8)))  short short8v;
typedef __attribute__((ext_vector_type(16))) float f32x16;

__device__ __forceinline__ uint32_t bf16b(float f) {
    uint32_t u = __float_as_uint(f);
    return (u + 0x7fffu + ((u >> 16) & 1u)) >> 16;   // RNE (prologue only)
}
__device__ __forceinline__ uint32_t cvtpk(float lo, float hi) {   // v_cvt_pk_bf16_f32 (RNE)
    __hip_bfloat162 b = __float22bfloat162_rn(make_float2(lo, hi));
    return *reinterpret_cast<uint32_t*>(&b);
}
__device__ __forceinline__ short8v ld8(const uint16_t* p) {   // 2x ds_read_b64
    short4v lo = *(const short4v*)p;
    short4v hi = *(const short4v*)(p + 4);
    return __builtin_shufflevector(lo, hi, 0, 1, 2, 3, 4, 5, 6, 7);
}
__device__ __forceinline__ short8v mk8(uint32_t w0, uint32_t w1, uint32_t w2, uint32_t w3) {
    union { uint32_t u[4]; short8v v; } c;
    c.u[0] = w0; c.u[1] = w1; c.u[2] = w2; c.u[3] = w3;
    return c.v;
}

// Barrier-free steady state: each wave owns its graphs + private LDS strip.
__global__ __launch_bounds__(256, 3) void egc_kernel(
    const float* __restrict__ x, const float* __restrict__ adj,
    const float* __restrict__ wself, const float* __restrict__ wneigh,
    const float* __restrict__ bias, float* __restrict__ out)
{
    __shared__ uint16_t sMem[4 * 32 * SROW];   // 4 wave strips (loop); W2T alias (prologue)
    __shared__ float sAdj[NNODE * NNODE];
    __shared__ float sBias[FDIM];

    const int t  = threadIdx.x;
    const int l  = t & 63;
    const int wv = t >> 6;
    const int n_ = l & 31;       // A.m / B.n / D.col
    const int h_ = l >> 5;       // k-half / D-row +4

    const int    gw    = blockIdx.x * 4 + wv;
    const size_t gbase = (size_t)gw * GPW;

    // issue graph-0 prefetch immediately (in flight across the prologue)
    const float4* xg = (const float4*)x + gbase * 272;
    float4 pf0, pf1, pf2, pf3, pf4;
    pf0 = xg[l]; pf1 = xg[l + 64]; pf2 = xg[l + 128]; pf3 = xg[l + 192];
    if (l < 16) pf4 = xg[256 + l];

    // ---- prologue: stage W2T[o][k] (k<64: Ws[k][o] else Wn[k-64][o]) into sMem
    for (int idx = t; idx < FDIM * 128; idx += 256) {
        int o = idx >> 7, k = idx & 127;
        float v = (k < 64) ? wself[k * 64 + o] : wneigh[(k - 64) * 64 + o];
        sMem[o * WSTR + k] = (uint16_t)bf16b(v);
    }
    for (int i = t; i < NNODE * NNODE; i += 256) sAdj[i] = adj[i];
    if (t < FDIM) sBias[t] = bias[t];
    __syncthreads();

    // W B-frags: B[k=16ks+8h_+e][n=32nt+n_]
    short8v wS[2][4], wN[2][4];
    #pragma unroll
    for (int nt = 0; nt < 2; ++nt)
        #pragma unroll
        for (int ks = 0; ks < 4; ++ks) {
            wS[nt][ks] = ld8(&sMem[(32 * nt + n_) * WSTR + 16 * ks + 8 * h_]);
            wN[nt][ks] = ld8(&sMem[(32 * nt + n_) * WSTR + 64 + 16 * ks + 8 * h_]);
        }
    const float bias0 = sBias[n_], bias1 = sBias[32 + n_];

    // adj A-frags in regs: A[m=n_][k=16ks+8h_+e] = adj[n_][k], explicit zero pad (no NaN)
    short8v adjA[2];
    #pragma unroll
    for (int ks = 0; ks < 2; ++ks) {
        short8v v;
        #pragma unroll
        for (int e = 0; e < 8; ++e) {
            int k = 16 * ks + 8 * h_ + e;
            float a = (n_ < NNODE && k < NNODE) ? sAdj[n_ * NNODE + k] : 0.f;
            v[e] = (short)bf16b(a);
        }
        adjA[ks] = v;
    }
    __syncthreads();
    // zero all strips once (pad rows 17..31 stay zero forever -> h pad rows finite-zero)
    for (int i = t; i < 4 * 32 * SROW; i += 256) sMem[i] = 0;
    __syncthreads();
    // ---- no __syncthreads below this line ----

    uint16_t* strip = &sMem[wv * 32 * SROW];
    float* outg = out + gbase * (size_t)(NNODE * FDIM);

    for (int g = 0; g < GPW; ++g) {
        // stage pf -> strip rows 0..16 (b64 writes; same-wave LDS is FIFO-ordered)
        {
            uint2 pk; int idx, row, c4;
            idx = l;       row = idx >> 4; c4 = (idx & 15) << 2;
            pk.x = cvtpk(pf0.x, pf0.y); pk.y = cvtpk(pf0.z, pf0.w);
            *(uint2*)&strip[row * SROW + c4] = pk;
            idx = l + 64;  row = idx >> 4; c4 = (idx & 15) << 2;
            pk.x = cvtpk(pf1.x, pf1.y); pk.y = cvtpk(pf1.z, pf1.w);
            *(uint2*)&strip[row * SROW + c4] = pk;
            idx = l + 128; row = idx >> 4; c4 = (idx & 15) << 2;
            pk.x = cvtpk(pf2.x, pf2.y); pk.y = cvtpk(pf2.z, pf2.w);
            *(uint2*)&strip[row * SROW + c4] = pk;
            idx = l + 192; row = idx >> 4; c4 = (idx & 15) << 2;
            pk.x = cvtpk(pf3.x, pf3.y); pk.y = cvtpk(pf3.z, pf3.w);
            *(uint2*)&strip[row * SROW + c4] = pk;
            if (l < 16) {
                pk.x = cvtpk(pf4.x, pf4.y); pk.y = cvtpk(pf4.z, pf4.w);
                *(uint2*)&strip[16 * SROW + (l << 2)] = pk;
            }
        }
        // prefetch next graph (hides HBM latency under MFMA below)
        if (g + 1 < GPW) {
            xg += 272;
            pf0 = xg[l]; pf1 = xg[l + 64]; pf2 = xg[l + 128]; pf3 = xg[l + 192];
            if (l < 16) pf4 = xg[256 + l];
        }

        // A-frags: A[m=node n_][k=16ks+8h_+e]  (rows 17..31 = zero pad)
        short8v a0 = ld8(&strip[n_ * SROW + 0  + 8 * h_]);
        short8v a1 = ld8(&strip[n_ * SROW + 16 + 8 * h_]);
        short8v a2 = ld8(&strip[n_ * SROW + 32 + 8 * h_]);
        short8v a3 = ld8(&strip[n_ * SROW + 48 + 8 * h_]);

        f32x16 s0, s1, h0, h1;
        #pragma unroll
        for (int r = 0; r < 16; ++r) { s0[r] = bias0; s1[r] = bias1; h0[r] = 0.f; h1[r] = 0.f; }

        // s = x@Ws + bias ; h = x@Wn   (K=64, 16 MFMA)
        s0 = __builtin_amdgcn_mfma_f32_32x32x16_bf16(a0, wS[0][0], s0, 0, 0, 0);
        s1 = __builtin_amdgcn_mfma_f32_32x32x16_bf16(a0, wS[1][0], s1, 0, 0, 0);
        h0 = __builtin_amdgcn_mfma_f32_32x32x16_bf16(a0, wN[0][0], h0, 0, 0, 0);
        h1 = __builtin_amdgcn_mfma_f32_32x32x16_bf16(a0, wN[1][0], h1, 0, 0, 0);
        s0 = __builtin_amdgcn_mfma_f32_32x32x16_bf16(a1, wS[0][1], s0, 0, 0, 0);
        s1 = __builtin_amdgcn_mfma_f32_32x32x16_bf16(a1, wS[1][1], s1, 0, 0, 0);
        h0 = __builtin_amdgcn_mfma_f32_32x32x16_bf16(a1, wN[0][1], h0, 0, 0, 0);
        h1 = __builtin_amdgcn_mfma_f32_32x32x16_bf16(a1, wN[1][1], h1, 0, 0, 0);
        s0 = __builtin_amdgcn_mfma_f32_32x32x16_bf16(a2, wS[0][2], s0, 0, 0, 0);
        s1 = __builtin_amdgcn_mfma_f32_32x32x16_bf16(a2, wS[1][2], s1, 0, 0, 0);
        h0 = __builtin_amdgcn_mfma_f32_32x32x16_bf16(a2, wN[0][2], h0, 0, 0, 0);
        h1 = __builtin_amdgcn_mfma_f32_32x32x16_bf16(a2, wN[1][2], h1, 0, 0, 0);
        s0 = __builtin_amdgcn_mfma_f32_32x32x16_bf16(a3, wS[0][3], s0, 0, 0, 0);
        s1 = __builtin_amdgcn_mfma_f32_32x32x16_bf16(a3, wS[1][3], s1, 0, 0, 0);
        h0 = __builtin_amdgcn_mfma_f32_32x32x16_bf16(a3, wN[0][3], h0, 0, 0, 0);
        h1 = __builtin_amdgcn_mfma_f32_32x32x16_bf16(a3, wN[1][3], h1, 0, 0, 0);

        // out += adj@h : h (D-layout) -> B-frag via cvt_pk pairs + permlane32_swap.
        // A=pk(H[rb],H[rb+1]) [h0-lanes rows(0,1)+16ks2 | h1 rows(4,5)+16ks2]
        // B=pk(H[rb+4],H[rb+5]) [h0 rows(8,9) | h1 rows(12,13)]
        // swap(A,B): A'=w0 (elems 0,1), B'=w2 (elems 4,5); C/D likewise -> w1,w3.
        #define HB_ADJ(SACC, HACC)                                                        \
        {                                                                                  \
            _Pragma("unroll")                                                              \
            for (int ks2 = 0; ks2 < 2; ++ks2) {                                            \
                const int rb = 8 * ks2;                                                    \
                uint32_t A01 = cvtpk(HACC[rb + 0], HACC[rb + 1]);                          \
                uint32_t C23 = cvtpk(HACC[rb + 2], HACC[rb + 3]);                          \
                uint32_t B45 = cvtpk(HACC[rb + 4], HACC[rb + 5]);                          \
                uint32_t D67 = cvtpk(HACC[rb + 6], HACC[rb + 7]);                          \
                asm("v_permlane32_swap_b32 %0, %1" : "+v"(A01), "+v"(B45));                \
                asm("v_permlane32_swap_b32 %0, %1" : "+v"(C23), "+v"(D67));                \
                SACC = __builtin_amdgcn_mfma_f32_32x32x16_bf16(                            \
                    adjA[ks2], mk8(A01, C23, B45, D67), SACC, 0, 0, 0);                    \
            }                                                                              \
        }
        HB_ADJ(s0, h0)
        HB_ADJ(s1, h1)
        #undef HB_ADJ

        // store: D[row=(r&3)+8*(r>>2)+4h_][col n_]; only regs 0..8 hold rows < 17
        {
            float* og = outg + (size_t)g * (NNODE * FDIM);
            #pragma unroll
            for (int r = 0; r < 9; ++r) {
                int row = (r & 3) + 8 * (r >> 2) + 4 * h_;
                if (row < NNODE) {
                    og[row * 64 + n_]      = s0[r];
                    og[row * 64 + 32 + n_] = s1[r];
                }
            }
        }
    }
}

extern "C" void kernel_launch(void* const* d_in, const int* in_sizes, int n_in,
                              void* d_out, int out_size, void* d_ws, size_t ws_size,
                              hipStream_t stream) {
    (void)in_sizes; (void)n_in; (void)d_ws; (void)ws_size; (void)out_size;
    const float* x      = (const float*)d_in[0];
    const float* adj    = (const float*)d_in[1];
    const float* wself  = (const float*)d_in[2];
    const float* wneigh = (const float*)d_in[3];
    const float* bias   = (const float*)d_in[4];
    float* out = (float*)d_out;
    egc_kernel<<<NBLOCK, 256, 0, stream>>>(x, adj, wself, wneigh, bias, out);
}

// Round 11
// 131.467 us; speedup vs baseline: 2.1116x; 2.1116x over previous
//
#include <hip/hip_runtime.h>
#include <hip/hip_bf16.h>
#include <stdint.h>

#define NNODE  17
#define FDIM   64
#define NBLOCK 1024
#define GPW    16           // graphs per wave: 1024 blk x 4 waves x 16 = 65536
#define SROW   68           // wave-strip col stride in u16 (136 B; conflict-free)
#define WSTR   132          // W2T staging stride in u16

typedef __attribute__((ext_vector_type(4)))  short short4v;
typedef __attribute__((ext_vector_type(8)))  short short8v;
typedef __attribute__((ext_vector_type(16))) float f32x16;
typedef __attribute__((ext_vector_type(2)))  unsigned int uint2v;

__device__ __forceinline__ uint32_t bf16b(float f) {
    uint32_t u = __float_as_uint(f);
    return (u + 0x7fffu + ((u >> 16) & 1u)) >> 16;   // RNE (prologue only)
}
__device__ __forceinline__ uint32_t cvtpk(float lo, float hi) {   // v_cvt_pk_bf16_f32 (RNE)
    __hip_bfloat162 b = __float22bfloat162_rn(make_float2(lo, hi));
    return *reinterpret_cast<uint32_t*>(&b);
}
__device__ __forceinline__ short8v ld8(const uint16_t* p) {   // 2x ds_read_b64
    short4v lo = *(const short4v*)p;
    short4v hi = *(const short4v*)(p + 4);
    return __builtin_shufflevector(lo, hi, 0, 1, 2, 3, 4, 5, 6, 7);
}
__device__ __forceinline__ short8v mk8(uint32_t w0, uint32_t w1, uint32_t w2, uint32_t w3) {
    union { uint32_t u[4]; short8v v; } c;
    c.u[0] = w0; c.u[1] = w1; c.u[2] = w2; c.u[3] = w3;
    return c.v;
}

// Barrier-free steady state: each wave owns its graphs + private LDS strip.
__global__ __launch_bounds__(256, 2) void egc_kernel(
    const float* __restrict__ x, const float* __restrict__ adj,
    const float* __restrict__ wself, const float* __restrict__ wneigh,
    const float* __restrict__ bias, float* __restrict__ out)
{
    __shared__ uint16_t sMem[4 * 32 * SROW];   // 4 wave strips (loop); W2T alias (prologue)
    __shared__ float sAdj[NNODE * NNODE];
    __shared__ float sBias[FDIM];

    const int t  = threadIdx.x;
    const int l  = t & 63;
    const int wv = t >> 6;
    const int n_ = l & 31;       // A.m / B.n / D.col
    const int h_ = l >> 5;       // k-half / D-row +4

    const int    gw    = blockIdx.x * 4 + wv;
    const size_t gbase = (size_t)gw * GPW;

    // issue graph-0 prefetch immediately (in flight across the prologue)
    const float4* xg = (const float4*)x + gbase * 272;
    float4 pf0, pf1, pf2, pf3, pf4;
    pf0 = xg[l]; pf1 = xg[l + 64]; pf2 = xg[l + 128]; pf3 = xg[l + 192];
    if (l < 16) pf4 = xg[256 + l];

    // ---- prologue: stage W2T[o][k] (k<64: Ws[k][o] else Wn[k-64][o]) into sMem
    for (int idx = t; idx < FDIM * 128; idx += 256) {
        int o = idx >> 7, k = idx & 127;
        float v = (k < 64) ? wself[k * 64 + o] : wneigh[(k - 64) * 64 + o];
        sMem[o * WSTR + k] = (uint16_t)bf16b(v);
    }
    for (int i = t; i < NNODE * NNODE; i += 256) sAdj[i] = adj[i];
    if (t < FDIM) sBias[t] = bias[t];
    __syncthreads();

    // W B-frags: B[k=16ks+8h_+e][n=32nt+n_]
    short8v wS[2][4], wN[2][4];
    #pragma unroll
    for (int nt = 0; nt < 2; ++nt)
        #pragma unroll
        for (int ks = 0; ks < 4; ++ks) {
            wS[nt][ks] = ld8(&sMem[(32 * nt + n_) * WSTR + 16 * ks + 8 * h_]);
            wN[nt][ks] = ld8(&sMem[(32 * nt + n_) * WSTR + 64 + 16 * ks + 8 * h_]);
        }
    const float bias0 = sBias[n_], bias1 = sBias[32 + n_];

    // adj A-frags in regs: A[m=n_][k=16ks+8h_+e] = adj[n_][k], explicit zero pad (no NaN)
    short8v adjA[2];
    #pragma unroll
    for (int ks = 0; ks < 2; ++ks) {
        short8v v;
        #pragma unroll
        for (int e = 0; e < 8; ++e) {
            int k = 16 * ks + 8 * h_ + e;
            float a = (n_ < NNODE && k < NNODE) ? sAdj[n_ * NNODE + k] : 0.f;
            v[e] = (short)bf16b(a);
        }
        adjA[ks] = v;
    }
    __syncthreads();
    // zero all strips once (pad rows 17..31 stay zero forever -> h pad rows finite-zero)
    for (int i = t; i < 4 * 32 * SROW; i += 256) sMem[i] = 0;
    __syncthreads();
    // ---- no __syncthreads below this line ----

    uint16_t* strip = &sMem[wv * 32 * SROW];
    float* outg = out + gbase * (size_t)(NNODE * FDIM);

    for (int g = 0; g < GPW; ++g) {
        // stage pf -> strip rows 0..16 (b64 writes; same-wave LDS is FIFO-ordered)
        {
            uint2 pk; int idx, row, c4;
            idx = l;       row = idx >> 4; c4 = (idx & 15) << 2;
            pk.x = cvtpk(pf0.x, pf0.y); pk.y = cvtpk(pf0.z, pf0.w);
            *(uint2*)&strip[row * SROW + c4] = pk;
            idx = l + 64;  row = idx >> 4; c4 = (idx & 15) << 2;
            pk.x = cvtpk(pf1.x, pf1.y); pk.y = cvtpk(pf1.z, pf1.w);
            *(uint2*)&strip[row * SROW + c4] = pk;
            idx = l + 128; row = idx >> 4; c4 = (idx & 15) << 2;
            pk.x = cvtpk(pf2.x, pf2.y); pk.y = cvtpk(pf2.z, pf2.w);
            *(uint2*)&strip[row * SROW + c4] = pk;
            idx = l + 192; row = idx >> 4; c4 = (idx & 15) << 2;
            pk.x = cvtpk(pf3.x, pf3.y); pk.y = cvtpk(pf3.z, pf3.w);
            *(uint2*)&strip[row * SROW + c4] = pk;
            if (l < 16) {
                pk.x = cvtpk(pf4.x, pf4.y); pk.y = cvtpk(pf4.z, pf4.w);
                *(uint2*)&strip[16 * SROW + (l << 2)] = pk;
            }
        }
        // prefetch next graph (hides HBM latency under MFMA below)
        if (g + 1 < GPW) {
            xg += 272;
            pf0 = xg[l]; pf1 = xg[l + 64]; pf2 = xg[l + 128]; pf3 = xg[l + 192];
            if (l < 16) pf4 = xg[256 + l];
        }

        // A-frags: A[m=node n_][k=16ks+8h_+e]  (rows 17..31 = zero pad)
        short8v a0 = ld8(&strip[n_ * SROW + 0  + 8 * h_]);
        short8v a1 = ld8(&strip[n_ * SROW + 16 + 8 * h_]);
        short8v a2 = ld8(&strip[n_ * SROW + 32 + 8 * h_]);
        short8v a3 = ld8(&strip[n_ * SROW + 48 + 8 * h_]);

        f32x16 s0, s1, h0, h1;
        #pragma unroll
        for (int r = 0; r < 16; ++r) { s0[r] = bias0; s1[r] = bias1; h0[r] = 0.f; h1[r] = 0.f; }

        // s = x@Ws + bias ; h = x@Wn   (K=64, 16 MFMA)
        s0 = __builtin_amdgcn_mfma_f32_32x32x16_bf16(a0, wS[0][0], s0, 0, 0, 0);
        s1 = __builtin_amdgcn_mfma_f32_32x32x16_bf16(a0, wS[1][0], s1, 0, 0, 0);
        h0 = __builtin_amdgcn_mfma_f32_32x32x16_bf16(a0, wN[0][0], h0, 0, 0, 0);
        h1 = __builtin_amdgcn_mfma_f32_32x32x16_bf16(a0, wN[1][0], h1, 0, 0, 0);
        s0 = __builtin_amdgcn_mfma_f32_32x32x16_bf16(a1, wS[0][1], s0, 0, 0, 0);
        s1 = __builtin_amdgcn_mfma_f32_32x32x16_bf16(a1, wS[1][1], s1, 0, 0, 0);
        h0 = __builtin_amdgcn_mfma_f32_32x32x16_bf16(a1, wN[0][1], h0, 0, 0, 0);
        h1 = __builtin_amdgcn_mfma_f32_32x32x16_bf16(a1, wN[1][1], h1, 0, 0, 0);
        s0 = __builtin_amdgcn_mfma_f32_32x32x16_bf16(a2, wS[0][2], s0, 0, 0, 0);
        s1 = __builtin_amdgcn_mfma_f32_32x32x16_bf16(a2, wS[1][2], s1, 0, 0, 0);
        h0 = __builtin_amdgcn_mfma_f32_32x32x16_bf16(a2, wN[0][2], h0, 0, 0, 0);
        h1 = __builtin_amdgcn_mfma_f32_32x32x16_bf16(a2, wN[1][2], h1, 0, 0, 0);
        s0 = __builtin_amdgcn_mfma_f32_32x32x16_bf16(a3, wS[0][3], s0, 0, 0, 0);
        s1 = __builtin_amdgcn_mfma_f32_32x32x16_bf16(a3, wS[1][3], s1, 0, 0, 0);
        h0 = __builtin_amdgcn_mfma_f32_32x32x16_bf16(a3, wN[0][3], h0, 0, 0, 0);
        h1 = __builtin_amdgcn_mfma_f32_32x32x16_bf16(a3, wN[1][3], h1, 0, 0, 0);

        // out += adj@h : h (D-layout) -> B-frag via cvt_pk + permlane32_swap
        // (register mapping hardware-verified by R10's passing run; no asm pinning here)
#if __has_builtin(__builtin_amdgcn_permlane32_swap)
        #define HB_ADJ(SACC, HACC)                                                        \
        {                                                                                  \
            _Pragma("unroll")                                                              \
            for (int ks2 = 0; ks2 < 2; ++ks2) {                                            \
                const int rb = 8 * ks2;                                                    \
                uint32_t A01 = cvtpk(HACC[rb + 0], HACC[rb + 1]);                          \
                uint32_t C23 = cvtpk(HACC[rb + 2], HACC[rb + 3]);                          \
                uint32_t B45 = cvtpk(HACC[rb + 4], HACC[rb + 5]);                          \
                uint32_t D67 = cvtpk(HACC[rb + 6], HACC[rb + 7]);                          \
                uint2v rA = __builtin_amdgcn_permlane32_swap(A01, B45, false, false);      \
                uint2v rC = __builtin_amdgcn_permlane32_swap(C23, D67, false, false);      \
                SACC = __builtin_amdgcn_mfma_f32_32x32x16_bf16(                            \
                    adjA[ks2], mk8(rA[0], rC[0], rA[1], rC[1]), SACC, 0, 0, 0);            \
            }                                                                              \
        }
#else
        #define HB_ADJ(SACC, HACC)                                                        \
        {                                                                                  \
            _Pragma("unroll")                                                              \
            for (int ks2 = 0; ks2 < 2; ++ks2) {                                            \
                const int rb = 8 * ks2;                                                    \
                float o0_ = __shfl_xor(h_ ? HACC[rb + 0] : HACC[rb + 4], 32);              \
                float o1_ = __shfl_xor(h_ ? HACC[rb + 1] : HACC[rb + 5], 32);              \
                float o2_ = __shfl_xor(h_ ? HACC[rb + 2] : HACC[rb + 6], 32);              \
                float o3_ = __shfl_xor(h_ ? HACC[rb + 3] : HACC[rb + 7], 32);              \
                uint32_t l01 = cvtpk(HACC[rb + 0], HACC[rb + 1]);                          \
                uint32_t l23 = cvtpk(HACC[rb + 2], HACC[rb + 3]);                          \
                uint32_t l45 = cvtpk(HACC[rb + 4], HACC[rb + 5]);                          \
                uint32_t l67 = cvtpk(HACC[rb + 6], HACC[rb + 7]);                          \
                uint32_t o01 = cvtpk(o0_, o1_);                                            \
                uint32_t o23 = cvtpk(o2_, o3_);                                            \
                uint32_t w0 = h_ ? o01 : l01;                                              \
                uint32_t w1 = h_ ? o23 : l23;                                              \
                uint32_t w2 = h_ ? l45 : o01;                                              \
                uint32_t w3 = h_ ? l67 : o23;                                              \
                SACC = __builtin_amdgcn_mfma_f32_32x32x16_bf16(                            \
                    adjA[ks2], mk8(w0, w1, w2, w3), SACC, 0, 0, 0);                        \
            }                                                                              \
        }
#endif
        HB_ADJ(s0, h0)
        HB_ADJ(s1, h1)
        #undef HB_ADJ

        // store: D[row=(r&3)+8*(r>>2)+4h_][col n_]; only regs 0..8 hold rows < 17
        {
            float* og = outg + (size_t)g * (NNODE * FDIM);
            #pragma unroll
            for (int r = 0; r < 9; ++r) {
                int row = (r & 3) + 8 * (r >> 2) + 4 * h_;
                if (row < NNODE) {
                    og[row * 64 + n_]      = s0[r];
                    og[row * 64 + 32 + n_] = s1[r];
                }
            }
        }
    }
}

extern "C" void kernel_launch(void* const* d_in, const int* in_sizes, int n_in,
                              void* d_out, int out_size, void* d_ws, size_t ws_size,
                              hipStream_t stream) {
    (void)in_sizes; (void)n_in; (void)d_ws; (void)ws_size; (void)out_size;
    const float* x      = (const float*)d_in[0];
    const float* adj    = (const float*)d_in[1];
    const float* wself  = (const float*)d_in[2];
    const float* wneigh = (const float*)d_in[3];
    const float* bias   = (const float*)d_in[4];
    float* out = (float*)d_out;
    egc_kernel<<<NBLOCK, 256, 0, stream>>>(x, adj, wself, wneigh, bias, out);
}